// Round 2
// baseline (4775.362 us; speedup 1.0000x reference)
//
#include <hip/hip_runtime.h>
#include <hip/hip_fp16.h>
#include <hip/hip_cooperative_groups.h>

namespace cg = cooperative_groups;

typedef _Float16 half8 __attribute__((ext_vector_type(8)));
typedef float floatx4 __attribute__((ext_vector_type(4)));

#define NB 128
#define NT 256
#define NIN 128
#define NH 1024

// ws layout (bytes): 8-deep h rings (so L2-inv is only needed every 8th phase)
// + fp16 x copy + barrier state
#define H0_OFF   0u          // 8 bufs x 128*1024 half = 2097152 B
#define H1_OFF   2097152u    // 2097152 B
#define X16_OFF  4194304u    // 128*256*128 half = 8388608 B
#define BAR_OFF  12582912u   // barrier region: 16 group lines @256B, root @4096, flag @4352

// LDS layout (bytes), carved from extern __shared__:
//  w0l: 16 cols x (1152+8) half = 37120
//  w1l: 16 cols x (2048+8) half = 65792   (base 37120)
//  gs0: 2 partials x 16 cols x 132 float = 16896 (base 102912) col-major gate tile
//  gs1: 2 partials x 16 cols x 132 float = 16896 (base 119808)
//  bs0/bs1: 16+16 float         =   128   (base 136704) -> total 136832
#define W0STRIDE 1160
#define W1STRIDE 2056
#define GSTRIDE  132
#define G2       (16 * GSTRIDE)   // float offset between the two K-partials
#define LDS_BYTES 136832

__device__ __forceinline__ float sigm(float x) { return 1.0f / (1.0f + __expf(-x)); }
__device__ __forceinline__ float tanh_fast(float x) { return 1.0f - 2.0f / (__expf(2.0f * x) + 1.0f); }

// h STORES: agent-scope relaxed atomic 2B stores — write-through past the
// non-coherent XCD L2 straight to LLC. After __syncthreads' vmcnt(0) drain
// these are globally visible: NO release (wbl2) fence needed anywhere.
__device__ __forceinline__ void st2_agent(_Float16* p, float v) {
    _Float16 hv = (_Float16)v;
    unsigned short u;
    __builtin_memcpy(&u, &hv, 2);
    __hip_atomic_store((unsigned short*)p, u, __ATOMIC_RELAXED, __HIP_MEMORY_SCOPE_AGENT);
}

// Two-level grid barrier: 16 groups x 16 WGs, separate LLC lines.
// Release side: NO cache fence (write-through h stores).
// Acquire side, ring-aware: h ring buffers are fresh addresses for 8
// consecutive phases, so the expensive agent fence (buffer_inv sc1: L1 +
// whole-XCD-L2 invalidate) is only needed every 8th epoch, right before ring
// addresses are reused. Other epochs need only a cheap per-CU L1 invalidate
// (buffer_inv sc0) to kill any (capacity-surviving) stale L1 h lines.
__device__ __forceinline__ void gbar_arrive(char* bar, unsigned epoch, int wg) {
    unsigned* gcnt = (unsigned*)(bar + (wg & 15) * 256);
    unsigned old = __hip_atomic_fetch_add(gcnt, 1u, __ATOMIC_RELAXED, __HIP_MEMORY_SCOPE_AGENT);
    if (old == epoch * 16u - 1u) {        // last of my group
        unsigned* rcnt = (unsigned*)(bar + 4096);
        unsigned rold = __hip_atomic_fetch_add(rcnt, 1u, __ATOMIC_RELAXED, __HIP_MEMORY_SCOPE_AGENT);
        if (rold == epoch * 16u - 1u) {   // last group overall
            unsigned* flag = (unsigned*)(bar + 4352);
            __hip_atomic_store(flag, epoch, __ATOMIC_RELAXED, __HIP_MEMORY_SCOPE_AGENT);
        }
    }
}
__device__ __forceinline__ void gbar_wait(char* bar, unsigned epoch) {
    unsigned* flag = (unsigned*)(bar + 4352);
    while (__hip_atomic_load(flag, __ATOMIC_RELAXED, __HIP_MEMORY_SCOPE_AGENT) < epoch)
        __builtin_amdgcn_s_sleep(1);
    if ((epoch & 7u) == 0u) {
        // ring-reuse boundary: invalidate L1 + XCD L2 so next 8 phases' cached
        // h loads (and the dense head) refill fresh from LLC
        __builtin_amdgcn_fence(__ATOMIC_ACQUIRE, "agent");
    } else {
        // L1-only invalidate: per-CU, cheap; XCD L2 keeps h/x lines warm
        asm volatile("s_waitcnt vmcnt(0)\n\tbuffer_inv sc0" ::: "memory");
    }
}

// 1024 threads = 16 waves/CU (4 waves/SIMD). K-split: wave group g = wave>>3
// computes the K-half [512g, 512g+512) of every gate dot product; the two
// partial gate tiles are summed during the activation stage. Doubles the
// waves available to hide the per-phase LLC refill of fresh h data (the
// measured ~690 cyc/line latency x in-flight-concurrency product) and to
// overlap LDS B-reads with VMEM stalls. 16 waves/CU forces <=128 VGPRs.
__global__ void __launch_bounds__(1024, 4)
lstm_persist(const float* __restrict__ x,
             const float* __restrict__ Wih0, const float* __restrict__ Whh0,
             const float* __restrict__ bih0, const float* __restrict__ bhh0,
             const float* __restrict__ Wih1, const float* __restrict__ Whh1,
             const float* __restrict__ bih1, const float* __restrict__ bhh1,
             const float* __restrict__ Wd, const float* __restrict__ bd,
             float* __restrict__ out, char* __restrict__ wsc)
{
    cg::grid_group grid = cg::this_grid();
    const int wg   = blockIdx.x;      // 0..255, owns h-cols [wg*4, wg*4+4)
    const int tid  = threadIdx.x;     // 0..1023
    const int wave = tid >> 6;        // 0..15
    const int g    = wave >> 3;       // K-half: 0 -> K[0,512), 1 -> K[512,1024)
    const int wrow = wave & 7;        // owns batch rows [wrow*16, wrow*16+16)
    const int lane = tid & 63;
    const int l15  = lane & 15;
    const int quad = lane >> 4;

    _Float16* h0b = (_Float16*)(wsc + H0_OFF);   // [8][128][1024] ring: h0[t] in buf t&7
    _Float16* h1b = (_Float16*)(wsc + H1_OFF);   // [8][128][1024] ring: h1[t] in buf t&7
    _Float16* x16 = (_Float16*)(wsc + X16_OFF);  // [128][256][128]
    char* bar = wsc + BAR_OFF;

    extern __shared__ char smem[];
    _Float16* w0l = (_Float16*)(smem);            // [16][1160]
    _Float16* w1l = (_Float16*)(smem + 37120);    // [16][2056]
    float*    gs0 = (float*)(smem + 102912);      // [2][16][132] col-major
    float*    gs1 = (float*)(smem + 119808);      // [2][16][132]
    float*    bs0 = (float*)(smem + 136704);      // [16]
    float*    bs1 = (float*)(smem + 136704 + 64); // [16]

    // ---------- init: stage this WG's weight slice into LDS (fp16) ----------
    for (int i = tid; i < 16 * 1152; i += 1024) {
        int c = i / 1152, k = i - c * 1152;
        int gcol = ((c >> 2) << 10) + (wg << 2) + (c & 3);
        float v = (k < NIN) ? Wih0[gcol * NIN + k] : Whh0[gcol * NH + (k - NIN)];
        w0l[c * W0STRIDE + k] = (_Float16)v;
    }
    for (int i = tid; i < 16 * 2048; i += 1024) {
        int c = i >> 11, k = i & 2047;
        int gcol = ((c >> 2) << 10) + (wg << 2) + (c & 3);
        float v = (k < NH) ? Wih1[gcol * NH + k] : Whh1[gcol * NH + (k - NH)];
        w1l[c * W1STRIDE + k] = (_Float16)v;
    }
    if (tid < 16) {
        int c = tid;
        int gcol = ((c >> 2) << 10) + (wg << 2) + (c & 3);
        bs0[c] = bih0[gcol] + bhh0[gcol];
        bs1[c] = bih1[gcol] + bhh1[gcol];
    }

    // ---------- init: zero h rings, convert x to fp16, reset barrier state ----------
    {
        const int gtid = wg * 1024 + tid;
        const int gsz  = 256 * 1024;  // 262144
        float* hz = (float*)wsc;      // both rings = 4 MiB = 1048576 floats
        for (int i = gtid; i < 1048576; i += gsz) hz[i] = 0.0f;
        for (int i = gtid; i < NB * NT * NIN; i += gsz) x16[i] = (_Float16)x[i];
        if (wg == 0 && tid < 18) {   // d_ws is poisoned 0xAA each run
            if (tid < 16)       *(unsigned*)(bar + tid * 256) = 0u;  // group counters
            else if (tid == 16) *(unsigned*)(bar + 4096) = 0u;       // root counter
            else                *(unsigned*)(bar + 4352) = 0u;       // flag
        }
    }
    // one slow cg sync with full fences: publishes zeros (into LLC) + barrier state
    __builtin_amdgcn_fence(__ATOMIC_RELEASE, "agent");
    grid.sync();
    __builtin_amdgcn_fence(__ATOMIC_ACQUIRE, "agent");

    float c0 = 0.0f, c1 = 0.0f;          // persistent cell state, 1 (b,hcol) pair/thread
    const int b_act = tid >> 2;          // batch row for activation stage (tid<512 only)
    const int jl    = tid & 3;           // local h-col
    const int hcol  = (wg << 2) + jl;

    // B-fragment row bases in LDS (n = l15), K-half g and quad*8 baked in.
    // w0l row layout: k in [0,128) = x-part, [128,1152) = h-part.
    const _Float16* w0row_x  = w0l + l15 * W0STRIDE + g * 64 + quad * 8;
    const _Float16* w0row_h  = w0l + l15 * W0STRIDE + NIN + g * 512 + quad * 8;
    const _Float16* w1row_h0 = w1l + l15 * W1STRIDE + g * 512 + quad * 8;        // W_ih1
    const _Float16* w1row_h1 = w1l + l15 * W1STRIDE + NH + g * 512 + quad * 8;   // W_hh1

    // x-part of layer0 gates for step p (h-independent), this wave's K-half of x
    auto xpart = [&](int p) -> floatx4 {
        floatx4 acc = {0.f, 0.f, 0.f, 0.f};
        const _Float16* arow_x = x16 + (size_t)(wrow * 16 + l15) * (NT * NIN) + p * NIN + g * 64 + quad * 8;
        #pragma unroll
        for (int kc = 0; kc < 2; ++kc) {
            half8 a = *(const half8*)(arow_x + kc * 32);
            half8 b = *(const half8*)(w0row_x + kc * 32);
            acc = __builtin_amdgcn_mfma_f32_16x16x32_f16(a, b, acc, 0, 0, 0);
        }
        return acc;
    };

    floatx4 accx = xpart(0);   // prologue for p=0

    // pipeline: phase p computes h0[p] (p<NT) and h1[p-1] (p>=1)
    // ring reads: h0[p-1] -> buf (p+7)&7 ; h1[p-2] -> buf (p+6)&7 (zeros pre-start)
    for (int p = 0; p <= NT; ++p) {
        const _Float16* h0prev = h0b + (size_t)((p + 7) & 7) * (NB * NH);  // h0[p-1]
        const _Float16* h1pp   = h1b + (size_t)((p + 6) & 7) * (NB * NH);  // h1[p-2]

        floatx4 acc0  = accx;  // x contribution precomputed during prior barrier window
        floatx4 acc1  = {0.f, 0.f, 0.f, 0.f};
        floatx4 acc1b = {0.f, 0.f, 0.f, 0.f};

        const _Float16* arow_h0 = h0prev + (size_t)(wrow * 16 + l15) * NH + g * 512 + quad * 8;
        const _Float16* arow_h1 = h1pp   + (size_t)(wrow * 16 + l15) * NH + g * 512 + quad * 8;

        // MLP-batched K loop over this wave's K-half (512 = 2 chunks x 8 j x 32):
        // 16 independent A-loads (8 h0 + 8 h1) per chunk, three acc chains.
        if (p >= 1 && p < NT) {
            #pragma unroll
            for (int c = 0; c < 2; ++c) {
                half8 a0[8], a1[8];
                #pragma unroll
                for (int j = 0; j < 8; ++j) a0[j] = *(const half8*)(arow_h0 + (c * 8 + j) * 32);
                #pragma unroll
                for (int j = 0; j < 8; ++j) a1[j] = *(const half8*)(arow_h1 + (c * 8 + j) * 32);
                #pragma unroll
                for (int j = 0; j < 8; ++j) {
                    half8 v0 = *(const half8*)(w0row_h  + (c * 8 + j) * 32);
                    half8 v1 = *(const half8*)(w1row_h0 + (c * 8 + j) * 32);
                    half8 v2 = *(const half8*)(w1row_h1 + (c * 8 + j) * 32);
                    acc0  = __builtin_amdgcn_mfma_f32_16x16x32_f16(a0[j], v0, acc0, 0, 0, 0);
                    acc1  = __builtin_amdgcn_mfma_f32_16x16x32_f16(a0[j], v1, acc1, 0, 0, 0);
                    acc1b = __builtin_amdgcn_mfma_f32_16x16x32_f16(a1[j], v2, acc1b, 0, 0, 0);
                }
            }
        } else if (p == NT) {  // layer1 only: h0[NT-1]·W_ih1 + h1[NT-2]·W_hh1
            #pragma unroll
            for (int c = 0; c < 2; ++c) {
                half8 a0[8], a1[8];
                #pragma unroll
                for (int j = 0; j < 8; ++j) a0[j] = *(const half8*)(arow_h0 + (c * 8 + j) * 32);
                #pragma unroll
                for (int j = 0; j < 8; ++j) a1[j] = *(const half8*)(arow_h1 + (c * 8 + j) * 32);
                #pragma unroll
                for (int j = 0; j < 8; ++j) {
                    half8 v1 = *(const half8*)(w1row_h0 + (c * 8 + j) * 32);
                    half8 v2 = *(const half8*)(w1row_h1 + (c * 8 + j) * 32);
                    acc1  = __builtin_amdgcn_mfma_f32_16x16x32_f16(a0[j], v1, acc1, 0, 0, 0);
                    acc1b = __builtin_amdgcn_mfma_f32_16x16x32_f16(a1[j], v2, acc1b, 0, 0, 0);
                }
            }
        }
        // p == 0: h buffers are all zeros — gate h-contributions are zero; skip.
        acc1 = acc1 + acc1b;

        // stash K-partial gate tiles to LDS, col-major: partial g at offset g*G2
        if (p < NT) *(floatx4*)&gs0[g * G2 + l15 * GSTRIDE + wrow * 16 + quad * 4] = acc0;
        if (p >= 1) *(floatx4*)&gs1[g * G2 + l15 * GSTRIDE + wrow * 16 + quad * 4] = acc1;
        __syncthreads();

        // activation: 1 (b, hcol) pair per thread (tid<512); sum the two K-partials
        if (tid < 512) {
            if (p < NT) {
                float gi = gs0[(jl)      * GSTRIDE + b_act] + gs0[G2 + (jl)      * GSTRIDE + b_act] + bs0[jl];
                float gf = gs0[(4 + jl)  * GSTRIDE + b_act] + gs0[G2 + (4 + jl)  * GSTRIDE + b_act] + bs0[4 + jl];
                float gg = gs0[(8 + jl)  * GSTRIDE + b_act] + gs0[G2 + (8 + jl)  * GSTRIDE + b_act] + bs0[8 + jl];
                float go = gs0[(12 + jl) * GSTRIDE + b_act] + gs0[G2 + (12 + jl) * GSTRIDE + b_act] + bs0[12 + jl];
                c0 = sigm(gf) * c0 + sigm(gi) * tanh_fast(gg);
                float h = sigm(go) * tanh_fast(c0);
                st2_agent(h0b + (size_t)(p & 7) * (NB * NH) + b_act * NH + hcol, h);   // h0[p]
            }
            if (p >= 1) {
                float gi = gs1[(jl)      * GSTRIDE + b_act] + gs1[G2 + (jl)      * GSTRIDE + b_act] + bs1[jl];
                float gf = gs1[(4 + jl)  * GSTRIDE + b_act] + gs1[G2 + (4 + jl)  * GSTRIDE + b_act] + bs1[4 + jl];
                float gg = gs1[(8 + jl)  * GSTRIDE + b_act] + gs1[G2 + (8 + jl)  * GSTRIDE + b_act] + bs1[8 + jl];
                float go = gs1[(12 + jl) * GSTRIDE + b_act] + gs1[G2 + (12 + jl) * GSTRIDE + b_act] + bs1[12 + jl];
                c1 = sigm(gf) * c1 + sigm(gi) * tanh_fast(gg);
                float h = sigm(go) * tanh_fast(c1);
                st2_agent(h1b + (size_t)((p + 7) & 7) * (NB * NH) + b_act * NH + hcol, h);  // h1[p-1]
            }
        }

        // ---- barrier with overlap: arrive (no release fence needed),
        // ---- compute next x-part during spin window, then wait + scoped inv.
        __syncthreads();                       // drains vmcnt: h-stores committed at LLC
        if (tid == 0) gbar_arrive(bar, (unsigned)(p + 1), wg);
        if (p + 1 < NT) accx = xpart(p + 1);   // h-independent work hides spin latency
        if (tid == 0) gbar_wait(bar, (unsigned)(p + 1));
        __syncthreads();
    }

    // dense head, parallel over batch: WG b computes out[b][0..1] from h1[255]
    // (ring buf 255&7 = 7; L2-inv at epoch 256 + L1-inv at epoch 257 make
    // cached loads fresh)
    if (wg < NB) {
        float p0 = 0.f, p1 = 0.f;
        if (tid < 512) {
            const _Float16* hrow = h1b + (size_t)7 * (NB * NH) + wg * NH;
            float hk0 = (float)hrow[tid * 2];
            float hk1 = (float)hrow[tid * 2 + 1];
            p0 = hk0 * Wd[tid * 2] + hk1 * Wd[tid * 2 + 1];
            p1 = hk0 * Wd[NH + tid * 2] + hk1 * Wd[NH + tid * 2 + 1];
        }
        #pragma unroll
        for (int off = 32; off; off >>= 1) {
            p0 += __shfl_down(p0, off);
            p1 += __shfl_down(p1, off);
        }
        float* red = gs0;  // reuse LDS (all threads past final __syncthreads)
        if (lane == 0) { red[wave * 2] = p0; red[wave * 2 + 1] = p1; }
        __syncthreads();
        if (tid < 2) {
            float s = bd[tid];
            #pragma unroll
            for (int w = 0; w < 16; ++w) s += red[w * 2 + tid];
            out[wg * 2 + tid] = tanhf(s);
        }
    }
}

extern "C" void kernel_launch(void* const* d_in, const int* in_sizes, int n_in,
                              void* d_out, int out_size, void* d_ws, size_t ws_size,
                              hipStream_t stream) {
    const float* x    = (const float*)d_in[0];
    const float* Wih0 = (const float*)d_in[1];
    const float* Whh0 = (const float*)d_in[2];
    const float* bih0 = (const float*)d_in[3];
    const float* bhh0 = (const float*)d_in[4];
    const float* Wih1 = (const float*)d_in[5];
    const float* Whh1 = (const float*)d_in[6];
    const float* bih1 = (const float*)d_in[7];
    const float* bhh1 = (const float*)d_in[8];
    const float* Wd   = (const float*)d_in[9];
    const float* bd   = (const float*)d_in[10];
    float* out = (float*)d_out;
    char* ws = (char*)d_ws;

    hipFuncSetAttribute((const void*)lstm_persist,
                        hipFuncAttributeMaxDynamicSharedMemorySize, LDS_BYTES);

    void* kargs[] = { &x, &Wih0, &Whh0, &bih0, &bhh0, &Wih1, &Whh1, &bih1, &bhh1,
                      &Wd, &bd, &out, &ws };
    hipLaunchCooperativeKernel((void*)lstm_persist, dim3(256), dim3(1024),
                               kargs, LDS_BYTES, stream);
}

// Round 3
// 3875.896 us; speedup vs baseline: 1.2321x; 1.2321x over previous
//
#include <hip/hip_runtime.h>
#include <hip/hip_fp16.h>
#include <hip/hip_cooperative_groups.h>

namespace cg = cooperative_groups;

typedef _Float16 half8 __attribute__((ext_vector_type(8)));
typedef float floatx4 __attribute__((ext_vector_type(4)));

#define NB 128
#define NT 256
#define NIN 128
#define NH 1024

// ws layout (bytes):
//  h rings: 8-deep (L2-inv only every 8th phase)
//  PART: pairwise K-partial exchange buffers [2 kg][128 cg][2 layers][32 n][64 b] fp32
//        (single slot: WAR-safe because next write is after the next global barrier,
//         and reads bypass L1/L2 via agent atomics -> no staleness, no ring needed)
#define H0_OFF   0u          // 8 x 128*1024 half = 2097152 B
#define H1_OFF   2097152u    // 2097152 B
#define PART_OFF 4194304u    // 2*128*4096 floats = 4194304 B
#define BAR_OFF  8388608u    // 16 group lines @256B, root @4096, flag @4352, pairflags @8192 (+16KB)

// LDS layout (bytes):
//  w0l: 32 n x (640+8) half  = 41472            [x(128) | Whh0 K-half(512)]
//  w1l: 32 n x (1024+8) half = 66048  @41472    [Wih1 K-half | Whh1 K-half]
//  gs0: 32 n x 132 float     = 16896  @107520   col-major gate tile (all 128 b)
//  gs1: 32 n x 132 float     = 16896  @124416
//  prl: 4096 float           = 16384  @141312   staged partner partial
//  bs0/bs1: 32+32 float      = 256    @157696   -> total 157952 (<160K, 1 WG/CU)
#define W0STRIDE 648
#define W1STRIDE 1032
#define GSTRIDE  132
#define LDS_BYTES 157952

__device__ __forceinline__ float sigm(float x) { return 1.0f / (1.0f + __expf(-x)); }
__device__ __forceinline__ float tanh_fast(float x) { return 1.0f - 2.0f / (__expf(2.0f * x) + 1.0f); }

// agent-scope relaxed stores: write-through past non-coherent XCD L2 to LLC.
// After __syncthreads' vmcnt(0) drain these are globally visible.
__device__ __forceinline__ void st2_agent(_Float16* p, float v) {
    _Float16 hv = (_Float16)v;
    unsigned short u;
    __builtin_memcpy(&u, &hv, 2);
    __hip_atomic_store((unsigned short*)p, u, __ATOMIC_RELAXED, __HIP_MEMORY_SCOPE_AGENT);
}
__device__ __forceinline__ void st4_agent(float* p, float v) {
    __hip_atomic_store(p, v, __ATOMIC_RELAXED, __HIP_MEMORY_SCOPE_AGENT);
}
__device__ __forceinline__ float ld4_agent(const float* p) {
    return __hip_atomic_load(p, __ATOMIC_RELAXED, __HIP_MEMORY_SCOPE_AGENT);
}

// Two-level grid barrier: 16 groups x 16 WGs. Ring-aware acquire fences:
// full agent fence (L1+XCD-L2 inv) only every 8th epoch (ring reuse boundary),
// cheap L1-only inv otherwise.
__device__ __forceinline__ void gbar_arrive(char* bar, unsigned epoch, int wg) {
    unsigned* gcnt = (unsigned*)(bar + (wg & 15) * 256);
    unsigned old = __hip_atomic_fetch_add(gcnt, 1u, __ATOMIC_RELAXED, __HIP_MEMORY_SCOPE_AGENT);
    if (old == epoch * 16u - 1u) {
        unsigned* rcnt = (unsigned*)(bar + 4096);
        unsigned rold = __hip_atomic_fetch_add(rcnt, 1u, __ATOMIC_RELAXED, __HIP_MEMORY_SCOPE_AGENT);
        if (rold == epoch * 16u - 1u) {
            unsigned* flag = (unsigned*)(bar + 4352);
            __hip_atomic_store(flag, epoch, __ATOMIC_RELAXED, __HIP_MEMORY_SCOPE_AGENT);
        }
    }
}
__device__ __forceinline__ void gbar_wait(char* bar, unsigned epoch) {
    unsigned* flag = (unsigned*)(bar + 4352);
    while (__hip_atomic_load(flag, __ATOMIC_RELAXED, __HIP_MEMORY_SCOPE_AGENT) < epoch)
        __builtin_amdgcn_s_sleep(1);
    if ((epoch & 7u) == 0u) {
        __builtin_amdgcn_fence(__ATOMIC_ACQUIRE, "agent");
    } else {
        asm volatile("s_waitcnt vmcnt(0)\n\tbuffer_inv sc0" ::: "memory");
    }
}

// K-split across WG pairs: WG (g = wg>>7, c = wg&127) owns 8 h-cols
// [c*8, c*8+8) and K-half [g*512, g*512+512). Halves per-CU global h reads
// (512->256 KB/phase) -- the R0-R2 invariant rate term. Partials summed via
// pairwise LLC exchange; activation ownership split by batch half
// (kgroup g owns batches [g*64, g*64+64)).
__global__ void __launch_bounds__(512, 2)
lstm_persist(const float* __restrict__ x,
             const float* __restrict__ Wih0, const float* __restrict__ Whh0,
             const float* __restrict__ bih0, const float* __restrict__ bhh0,
             const float* __restrict__ Wih1, const float* __restrict__ Whh1,
             const float* __restrict__ bih1, const float* __restrict__ bhh1,
             const float* __restrict__ Wd, const float* __restrict__ bd,
             float* __restrict__ out, char* __restrict__ wsc)
{
    cg::grid_group grid = cg::this_grid();
    const int wg   = blockIdx.x;      // 0..255
    const int g    = wg >> 7;         // kgroup: K-half
    const int c    = wg & 127;        // colgroup: h-cols [c*8, c*8+8)
    const int tid  = threadIdx.x;     // 0..511
    const int r    = tid >> 6;        // rowgroup 0..7: batches [r*16, r*16+16)
    const int lane = tid & 63;
    const int l15  = lane & 15;
    const int quad = lane >> 4;

    _Float16* h0b = (_Float16*)(wsc + H0_OFF);   // [8][128][1024] ring
    _Float16* h1b = (_Float16*)(wsc + H1_OFF);   // [8][128][1024] ring
    char* bar = wsc + BAR_OFF;
    float* part = (float*)(wsc + PART_OFF);
    float* my_part = part + (size_t)(g * 128 + c) * 4096;        // my partial for partner's batches
    float* pr_part = part + (size_t)((1 - g) * 128 + c) * 4096;  // partner's partial for my batches
    unsigned* myflag = (unsigned*)(bar + 8192 + c * 128 + g * 4);
    unsigned* prflag = (unsigned*)(bar + 8192 + c * 128 + (1 - g) * 4);

    extern __shared__ char smem[];
    _Float16* w0l = (_Float16*)(smem);            // [32][648]
    _Float16* w1l = (_Float16*)(smem + 41472);    // [32][1032]
    float*    gs0 = (float*)(smem + 107520);      // [32][132] col-major
    float*    gs1 = (float*)(smem + 124416);      // [32][132]
    float*    prl = (float*)(smem + 141312);      // [4096] staged partner partial
    float*    bs0 = (float*)(smem + 157696);      // [32]
    float*    bs1 = (float*)(smem + 157696 + 128);// [32]

    // ---------- init: stage weight slice (8 cols x K-half) into LDS ----------
    // n in [0,32): gate gt=n>>3, local col cl=n&7 -> gcol = gt*1024 + c*8 + cl
    for (int i = tid; i < 32 * 640; i += 512) {
        int n = i / 640, k = i - n * 640;
        int gcol = ((n >> 3) << 10) + (c << 3) + (n & 7);
        float v = (k < NIN) ? Wih0[gcol * NIN + k] : Whh0[gcol * NH + g * 512 + (k - NIN)];
        w0l[n * W0STRIDE + k] = (_Float16)v;
    }
    for (int i = tid; i < 32 * 1024; i += 512) {
        int n = i >> 10, k = i & 1023;
        int gcol = ((n >> 3) << 10) + (c << 3) + (n & 7);
        float v = (k < 512) ? Wih1[gcol * NH + g * 512 + k] : Whh1[gcol * NH + g * 512 + (k - 512)];
        w1l[n * W1STRIDE + k] = (_Float16)v;
    }
    if (tid < 32) {
        int n = tid;
        int gcol = ((n >> 3) << 10) + (c << 3) + (n & 7);
        bs0[n] = bih0[gcol] + bhh0[gcol];
        bs1[n] = bih1[gcol] + bhh1[gcol];
    }

    // ---------- init: zero h rings + barrier/pairflag state ----------
    {
        const int gtid = wg * 512 + tid;
        const int gsz  = 256 * 512;
        float* hz = (float*)wsc;     // both h rings = 4 MiB = 1048576 floats
        for (int i = gtid; i < 1048576; i += gsz) hz[i] = 0.0f;
        if (wg == 0) {
            if (tid < 18) {
                if (tid < 16)       *(unsigned*)(bar + tid * 256) = 0u;
                else if (tid == 16) *(unsigned*)(bar + 4096) = 0u;
                else                *(unsigned*)(bar + 4352) = 0u;
            }
            for (int i = tid; i < 4096; i += 512) *(unsigned*)(bar + 8192 + i * 4) = 0u;
        }
    }
    __builtin_amdgcn_fence(__ATOMIC_RELEASE, "agent");
    grid.sync();
    __builtin_amdgcn_fence(__ATOMIC_ACQUIRE, "agent");

    float c0 = 0.0f, c1 = 0.0f;          // cell state: 1 (b,hcol) pair/thread
    const int bh_   = tid >> 3;          // local batch 0..63
    const int cl_   = tid & 7;           // local h-col 0..7
    const int bact  = g * 64 + bh_;      // owned global batch
    const int hcol  = (c << 3) + cl_;

    // B-fragment row bases in LDS (per nt tile), quad*8 baked in
    const _Float16* bw0[2];  const _Float16* bw1i[2];  const _Float16* bw1h[2];  const _Float16* bx[2];
    #pragma unroll
    for (int nt = 0; nt < 2; ++nt) {
        bw0[nt]  = w0l + (nt * 16 + l15) * W0STRIDE + NIN + quad * 8;  // Whh0 K-half
        bw1i[nt] = w1l + (nt * 16 + l15) * W1STRIDE + quad * 8;        // Wih1 K-half
        bw1h[nt] = bw1i[nt] + 512;                                     // Whh1 K-half
        bx[nt]   = w0l + (nt * 16 + l15) * W0STRIDE + quad * 8;        // x weights (full 128)
    }
    const int aoff = (r * 16 + l15) * NH + g * 512 + quad * 8;         // A-row offset in h arrays

    floatx4 accx0 = {0.f,0.f,0.f,0.f}, accx1 = {0.f,0.f,0.f,0.f};

    // x-part of layer0 gates (h-independent, g==0 WGs only), fp32 x converted on the fly
    auto xpart = [&](int t) {
        floatx4 ax0 = {0.f,0.f,0.f,0.f}, ax1 = {0.f,0.f,0.f,0.f};
        const float* xr = x + (size_t)(r * 16 + l15) * (NT * NIN) + t * NIN + quad * 8;
        #pragma unroll
        for (int j = 0; j < 4; ++j) {
            floatx4 f0 = *(const floatx4*)(xr + j * 32);
            floatx4 f1 = *(const floatx4*)(xr + j * 32 + 4);
            half8 a;
            a[0]=(_Float16)f0[0]; a[1]=(_Float16)f0[1]; a[2]=(_Float16)f0[2]; a[3]=(_Float16)f0[3];
            a[4]=(_Float16)f1[0]; a[5]=(_Float16)f1[1]; a[6]=(_Float16)f1[2]; a[7]=(_Float16)f1[3];
            half8 b0 = *(const half8*)(bx[0] + j * 32);
            half8 b1 = *(const half8*)(bx[1] + j * 32);
            ax0 = __builtin_amdgcn_mfma_f32_16x16x32_f16(a, b0, ax0, 0, 0, 0);
            ax1 = __builtin_amdgcn_mfma_f32_16x16x32_f16(a, b1, ax1, 0, 0, 0);
        }
        accx0 = ax0; accx1 = ax1;
    };

    if (g == 0) xpart(0);   // prologue

    // phase p: computes h0[p] (p<NT) and h1[p-1] (p>=1)
    // ring reads: h0[p-1] -> buf (p+7)&7 ; h1[p-2] -> buf (p+6)&7
    for (int p = 0; p <= NT; ++p) {
        const _Float16* arow_h0 = h0b + (size_t)((p + 7) & 7) * (NB * NH) + aoff;
        const _Float16* arow_h1 = h1b + (size_t)((p + 6) & 7) * (NB * NH) + aoff;

        floatx4 acc0[2]  = { accx0, accx1 };
        floatx4 acc1[2]  = { {0.f,0.f,0.f,0.f}, {0.f,0.f,0.f,0.f} };
        floatx4 acc1b[2] = { {0.f,0.f,0.f,0.f}, {0.f,0.f,0.f,0.f} };

        if (p >= 1 && p < NT) {
            #pragma unroll
            for (int jb = 0; jb < 4; ++jb) {
                half8 a0v[4], a1v[4];
                #pragma unroll
                for (int j = 0; j < 4; ++j) a0v[j] = *(const half8*)(arow_h0 + (jb * 4 + j) * 32);
                #pragma unroll
                for (int j = 0; j < 4; ++j) a1v[j] = *(const half8*)(arow_h1 + (jb * 4 + j) * 32);
                #pragma unroll
                for (int j = 0; j < 4; ++j) {
                    #pragma unroll
                    for (int nt = 0; nt < 2; ++nt) {
                        half8 v0 = *(const half8*)(bw0[nt]  + (jb * 4 + j) * 32);
                        half8 v1 = *(const half8*)(bw1i[nt] + (jb * 4 + j) * 32);
                        half8 v2 = *(const half8*)(bw1h[nt] + (jb * 4 + j) * 32);
                        acc0[nt]  = __builtin_amdgcn_mfma_f32_16x16x32_f16(a0v[j], v0, acc0[nt], 0, 0, 0);
                        acc1[nt]  = __builtin_amdgcn_mfma_f32_16x16x32_f16(a0v[j], v1, acc1[nt], 0, 0, 0);
                        acc1b[nt] = __builtin_amdgcn_mfma_f32_16x16x32_f16(a1v[j], v2, acc1b[nt], 0, 0, 0);
                    }
                }
            }
        } else if (p == NT) {  // layer1 only
            #pragma unroll
            for (int jb = 0; jb < 4; ++jb) {
                half8 a0v[4], a1v[4];
                #pragma unroll
                for (int j = 0; j < 4; ++j) a0v[j] = *(const half8*)(arow_h0 + (jb * 4 + j) * 32);
                #pragma unroll
                for (int j = 0; j < 4; ++j) a1v[j] = *(const half8*)(arow_h1 + (jb * 4 + j) * 32);
                #pragma unroll
                for (int j = 0; j < 4; ++j) {
                    #pragma unroll
                    for (int nt = 0; nt < 2; ++nt) {
                        half8 v1 = *(const half8*)(bw1i[nt] + (jb * 4 + j) * 32);
                        half8 v2 = *(const half8*)(bw1h[nt] + (jb * 4 + j) * 32);
                        acc1[nt]  = __builtin_amdgcn_mfma_f32_16x16x32_f16(a0v[j], v1, acc1[nt], 0, 0, 0);
                        acc1b[nt] = __builtin_amdgcn_mfma_f32_16x16x32_f16(a1v[j], v2, acc1b[nt], 0, 0, 0);
                    }
                }
            }
        }
        // p == 0: h rings are zeros; gates = x-part only
        acc1[0] = acc1[0] + acc1b[0];
        acc1[1] = acc1[1] + acc1b[1];

        // stash K-partial gate tiles (all 128 batches) to LDS, col-major
        #pragma unroll
        for (int nt = 0; nt < 2; ++nt) {
            if (p < NT)  *(floatx4*)&gs0[(nt * 16 + l15) * GSTRIDE + r * 16 + quad * 4] = acc0[nt];
            if (p >= 1)  *(floatx4*)&gs1[(nt * 16 + l15) * GSTRIDE + r * 16 + quad * 4] = acc1[nt];
        }
        __syncthreads();

        // ---- pairwise K-partial exchange: send my partial for PARTNER's batches
        // idx = l*2048 + n*64 + bo  (l=layer, n=gatecol, bo=partner-local batch)
        #pragma unroll
        for (int rep = 0; rep < 8; ++rep) {
            int idx = rep * 512 + tid;
            int l = idx >> 11, rem = idx & 2047;
            int n = rem >> 6, bo = (rem & 63) + (1 - g) * 64;
            float v = l ? gs1[n * GSTRIDE + bo] : gs0[n * GSTRIDE + bo];
            st4_agent(my_part + idx, v);
        }
        __syncthreads();                       // drains vmcnt: partial stores at LLC
        if (tid == 0) {
            __hip_atomic_store(myflag, (unsigned)(p + 1), __ATOMIC_RELAXED, __HIP_MEMORY_SCOPE_AGENT);
            while (__hip_atomic_load(prflag, __ATOMIC_RELAXED, __HIP_MEMORY_SCOPE_AGENT) < (unsigned)(p + 1))
                __builtin_amdgcn_s_sleep(1);
        }
        __syncthreads();                       // partner's partial is at LLC now

        // stage partner partial into LDS (dense agent loads bypass stale L1/L2)
        #pragma unroll
        for (int rep = 0; rep < 8; ++rep) {
            int idx = rep * 512 + tid;
            prl[idx] = ld4_agent(pr_part + idx);
        }
        __syncthreads();

        // activation: this WG owns batches [g*64, g*64+64) for its 8 h-cols
        {
            if (p < NT) {
                float gi = gs0[(cl_)      * GSTRIDE + bact] + prl[(cl_)      * 64 + bh_] + bs0[cl_];
                float gf = gs0[(8 + cl_)  * GSTRIDE + bact] + prl[(8 + cl_)  * 64 + bh_] + bs0[8 + cl_];
                float gg = gs0[(16 + cl_) * GSTRIDE + bact] + prl[(16 + cl_) * 64 + bh_] + bs0[16 + cl_];
                float go = gs0[(24 + cl_) * GSTRIDE + bact] + prl[(24 + cl_) * 64 + bh_] + bs0[24 + cl_];
                c0 = sigm(gf) * c0 + sigm(gi) * tanh_fast(gg);
                float h = sigm(go) * tanh_fast(c0);
                st2_agent(h0b + (size_t)(p & 7) * (NB * NH) + bact * NH + hcol, h);   // h0[p]
            }
            if (p >= 1) {
                float gi = gs1[(cl_)      * GSTRIDE + bact] + prl[2048 + (cl_)      * 64 + bh_] + bs1[cl_];
                float gf = gs1[(8 + cl_)  * GSTRIDE + bact] + prl[2048 + (8 + cl_)  * 64 + bh_] + bs1[8 + cl_];
                float gg = gs1[(16 + cl_) * GSTRIDE + bact] + prl[2048 + (16 + cl_) * 64 + bh_] + bs1[16 + cl_];
                float go = gs1[(24 + cl_) * GSTRIDE + bact] + prl[2048 + (24 + cl_) * 64 + bh_] + bs1[24 + cl_];
                c1 = sigm(gf) * c1 + sigm(gi) * tanh_fast(gg);
                float h = sigm(go) * tanh_fast(c1);
                st2_agent(h1b + (size_t)((p + 7) & 7) * (NB * NH) + bact * NH + hcol, h);  // h1[p-1]
            }
        }

        // ---- global barrier with overlap: next x-part hides the spin window
        __syncthreads();                       // drains vmcnt: h-stores at LLC
        if (tid == 0) gbar_arrive(bar, (unsigned)(p + 1), wg);
        if (g == 0 && p + 1 < NT) xpart(p + 1);
        if (tid == 0) gbar_wait(bar, (unsigned)(p + 1));
        __syncthreads();
    }

    // dense head: WG b (<128) computes out[b][0..1] from h1[255] (ring slot 7)
    if (wg < NB) {
        const _Float16* hrow = h1b + (size_t)7 * (NB * NH) + wg * NH;
        float hk0 = (float)hrow[tid * 2];
        float hk1 = (float)hrow[tid * 2 + 1];
        float p0 = hk0 * Wd[tid * 2] + hk1 * Wd[tid * 2 + 1];
        float p1 = hk0 * Wd[NH + tid * 2] + hk1 * Wd[NH + tid * 2 + 1];
        #pragma unroll
        for (int off = 32; off; off >>= 1) {
            p0 += __shfl_down(p0, off);
            p1 += __shfl_down(p1, off);
        }
        float* red = gs0;  // reuse LDS
        if (lane == 0) { red[r * 2] = p0; red[r * 2 + 1] = p1; }
        __syncthreads();
        if (tid < 2) {
            float s = bd[tid];
            #pragma unroll
            for (int w = 0; w < 8; ++w) s += red[w * 2 + tid];
            out[wg * 2 + tid] = tanhf(s);
        }
    }
}

extern "C" void kernel_launch(void* const* d_in, const int* in_sizes, int n_in,
                              void* d_out, int out_size, void* d_ws, size_t ws_size,
                              hipStream_t stream) {
    const float* x    = (const float*)d_in[0];
    const float* Wih0 = (const float*)d_in[1];
    const float* Whh0 = (const float*)d_in[2];
    const float* bih0 = (const float*)d_in[3];
    const float* bhh0 = (const float*)d_in[4];
    const float* Wih1 = (const float*)d_in[5];
    const float* Whh1 = (const float*)d_in[6];
    const float* bih1 = (const float*)d_in[7];
    const float* bhh1 = (const float*)d_in[8];
    const float* Wd   = (const float*)d_in[9];
    const float* bd   = (const float*)d_in[10];
    float* out = (float*)d_out;
    char* ws = (char*)d_ws;

    hipFuncSetAttribute((const void*)lstm_persist,
                        hipFuncAttributeMaxDynamicSharedMemorySize, LDS_BYTES);

    void* kargs[] = { &x, &Wih0, &Whh0, &bih0, &bhh0, &Wih1, &Whh1, &bih1, &bhh1,
                      &Wd, &bd, &out, &ws };
    hipLaunchCooperativeKernel((void*)lstm_persist, dim3(256), dim3(512),
                               kargs, LDS_BYTES, stream);
}